// Round 4
// baseline (1085.920 us; speedup 1.0000x reference)
//
#include <hip/hip_runtime.h>
#include <hip/hip_bf16.h>

typedef unsigned short u16;
typedef unsigned int u32;
using bf16x8 = __attribute__((ext_vector_type(8))) __bf16;
using u16x8  = __attribute__((ext_vector_type(8))) u16;
using f32x4  = __attribute__((ext_vector_type(4))) float;

#define DEV __device__ __forceinline__

constexpr int Bv = 4, Sq = 2048, Dm = 1024, Hh = 16, HDim = 64;
constexpr int M = Bv * Sq;      // 8192 rows
constexpr int NK = Dm;          // 1024 (N and K of every GEMM)

DEV float bf2f(u16 u) { union { u32 i; float f; } x; x.i = (u32)u << 16; return x.f; }
DEV u16 f2bf(float f) {
  union { float f; u32 i; } x; x.f = f;
  u32 r = (x.i + 0x7fff + ((x.i >> 16) & 1)) >> 16;  // RNE
  return (u16)r;
}

// Dtype probe: low u16 of each u32 of x. bf16-world: that's element 2i, a
// sane bf16 (exp in [116,129]) -> ~64/64 hits. fp32-world: low mantissa
// bits, ~uniform -> ~10/64 hits. Deterministic (x is pristine input).
DEV bool detect_bf16(const u32* xw) {
  int c = 0;
#pragma unroll
  for (int i = 0; i < 64; ++i) {
    u32 e = (xw[i] >> 7) & 0xFF;          // exp field of low half-word
    c += (e >= 100 && e <= 140) ? 1 : 0;
  }
  return c >= 40;
}

// ------------------------------------------------------------------
// Canonicalize x -> bf16 xb[M][D].
__global__ __launch_bounds__(256) void convert_x(const u32* __restrict__ xw,
                                                 u16* __restrict__ xb) {
  const bool isb = detect_bf16(xw);
  const size_t i0 = ((size_t)blockIdx.x * 256 + threadIdx.x) * 8;
  if (isb) {
    *(u16x8*)(xb + i0) = *(const u16x8*)((const u16*)xw + i0);
  } else {
    const float* xf = (const float*)xw;
    u16x8 r;
#pragma unroll
    for (int j = 0; j < 8; ++j) r[j] = f2bf(xf[i0 + j]);
    *(u16x8*)(xb + i0) = r;
  }
}

// Canonicalize bias/gamma/beta -> bf16 (3 vectors of 1024).
struct VPtrs { const void* v[3]; };
__global__ __launch_bounds__(256) void convert_vec(VPtrs vp, u16* __restrict__ dst,
                                                   const u32* __restrict__ xw) {
  const bool isb = detect_bf16(xw);
  const int z = blockIdx.y, i = blockIdx.x * 256 + threadIdx.x;
  u16* d = dst + z * Dm;
  if (isb) d[i] = ((const u16*)vp.v[z])[i];
  else     d[i] = f2bf(((const float*)vp.v[z])[i]);
}

// ------------------------------------------------------------------
// Weight transpose + canonicalize: W[K][N] (fp32 or bf16) -> WT[N][K] bf16.
struct WPtrs { const void* w[6]; };
__global__ __launch_bounds__(256) void transpose_w(WPtrs wp, u16* __restrict__ wt,
                                                   const u32* __restrict__ xw) {
  const bool isb = detect_bf16(xw);
  const int z = blockIdx.y, kk = blockIdx.x, tid = threadIdx.x;
  u16* T = wt + (size_t)z * Dm * Dm;
  if (isb) {
    const u16* W = (const u16*)wp.w[z];
#pragma unroll
    for (int j = 0; j < 4; ++j) {
      int n = tid + j * 256;
      T[(size_t)n * Dm + kk] = W[(size_t)kk * Dm + n];
    }
  } else {
    const float* W = (const float*)wp.w[z];
#pragma unroll
    for (int j = 0; j < 4; ++j) {
      int n = tid + j * 256;
      T[(size_t)n * Dm + kk] = f2bf(W[(size_t)kk * Dm + n]);
    }
  }
}

// ------------------------------------------------------------------
// bf16 GEMM, C[M,N] = A[M,K] @ B, B pre-transposed Bt[N][K].
// BM=BN=128, BK=32, 256 thr (4 waves), wave = 64x64 (4x4 16x16x32 MFMA).
// mode 0: bf16 store; mode 1: sigmoid(x+bias)->bf16; mode 2: final store
// (bf16 or fp32 chosen by runtime dtype probe).
struct GemmEntry { const u16* wt; void* out; int mode; };
struct GemmArgs { GemmEntry e[6]; const u16* bias; };

__global__ __launch_bounds__(256) void gemm_bt(const u16* __restrict__ A, GemmArgs ga,
                                               int zbase, const u32* __restrict__ xw) {
  const int z = zbase + blockIdx.z;
  const u16* Bt = ga.e[z].wt;
  const int m0 = blockIdx.x * 128, n0 = blockIdx.y * 128;
  __shared__ __align__(16) u16 As[128 * 32];
  __shared__ __align__(16) u16 Bs[128 * 32];
  const int tid = threadIdx.x, lane = tid & 63;
  const int wm = ((tid >> 6) & 1) * 64, wn = ((tid >> 6) >> 1) * 64;
  const int lr = lane & 15, lk = (lane >> 4) * 8;

  f32x4 acc[4][4] = {};

  const int r0 = tid >> 2, c0 = (tid & 3) * 8;   // staging: 16B/thread x2 each
  const u16* Ag = A + (size_t)(m0 + r0) * NK + c0;
  const u16* Bg = Bt + (size_t)(n0 + r0) * NK + c0;

  for (int kt = 0; kt < NK; kt += 32) {
    u16x8 a0 = *(const u16x8*)(Ag + kt);
    u16x8 a1 = *(const u16x8*)(Ag + (size_t)64 * NK + kt);
    u16x8 b0 = *(const u16x8*)(Bg + kt);
    u16x8 b1 = *(const u16x8*)(Bg + (size_t)64 * NK + kt);
    __syncthreads();
    *(u16x8*)(As + tid * 8) = a0;            // element ofs tid*8 == r0*32+c0
    *(u16x8*)(As + 2048 + tid * 8) = a1;     // rows +64
    *(u16x8*)(Bs + tid * 8) = b0;
    *(u16x8*)(Bs + 2048 + tid * 8) = b1;
    __syncthreads();
    bf16x8 af[4], bfr[4];
#pragma unroll
    for (int i = 0; i < 4; ++i) af[i] = *(const bf16x8*)(As + (wm + i * 16 + lr) * 32 + lk);
#pragma unroll
    for (int j = 0; j < 4; ++j) bfr[j] = *(const bf16x8*)(Bs + (wn + j * 16 + lr) * 32 + lk);
#pragma unroll
    for (int i = 0; i < 4; ++i)
#pragma unroll
      for (int j = 0; j < 4; ++j)
        acc[i][j] = __builtin_amdgcn_mfma_f32_16x16x32_bf16(af[i], bfr[j], acc[i][j], 0, 0, 0);
  }

  const int mode = ga.e[z].mode;
  const int rb = m0 + wm + (lane >> 4) * 4;  // C/D: col=lane&15, row=quad*4+reg
  const int cb = n0 + wn + lr;
  if (mode == 0) {
    u16* O = (u16*)ga.e[z].out;
#pragma unroll
    for (int i = 0; i < 4; ++i)
#pragma unroll
      for (int j = 0; j < 4; ++j)
#pragma unroll
        for (int r = 0; r < 4; ++r)
          O[(size_t)(rb + i * 16 + r) * NK + cb + j * 16] = f2bf(acc[i][j][r]);
  } else if (mode == 1) {
    u16* O = (u16*)ga.e[z].out;
#pragma unroll
    for (int j = 0; j < 4; ++j) {
      float bb = bf2f(ga.bias[cb + j * 16]);
#pragma unroll
      for (int i = 0; i < 4; ++i)
#pragma unroll
        for (int r = 0; r < 4; ++r) {
          float val = acc[i][j][r] + bb;
          O[(size_t)(rb + i * 16 + r) * NK + cb + j * 16] = f2bf(1.f / (1.f + __expf(-val)));
        }
    }
  } else {
    const bool isb = detect_bf16(xw);
    if (isb) {
      u16* O = (u16*)ga.e[z].out;
#pragma unroll
      for (int i = 0; i < 4; ++i)
#pragma unroll
        for (int j = 0; j < 4; ++j)
#pragma unroll
          for (int r = 0; r < 4; ++r)
            O[(size_t)(rb + i * 16 + r) * NK + cb + j * 16] = f2bf(acc[i][j][r]);
    } else {
      float* O = (float*)ga.e[z].out;
#pragma unroll
      for (int i = 0; i < 4; ++i)
#pragma unroll
        for (int j = 0; j < 4; ++j)
#pragma unroll
          for (int r = 0; r < 4; ++r)
            O[(size_t)(rb + i * 16 + r) * NK + cb + j * 16] = acc[i][j][r];
    }
  }
}

// ------------------------------------------------------------------
// Recurrent scan: one wave per (b,h,i) row; lane j holds state column j.
// state_j = g[i]*state_j + v[i]*k_j ; out = sum_j state_j*q_j (shfl reduce).
// Out written coalesced every 64 steps to ot[B*H*HD][S] (bf16).
__global__ __launch_bounds__(256) void scan_kernel(
    const u16* __restrict__ q, const u16* __restrict__ k,
    const u16* __restrict__ v, const u16* __restrict__ g,
    u16* __restrict__ ot) {
  const int w = blockIdx.x * 4 + (threadIdx.x >> 6);  // 0..4095 = b*1024+h*64+i
  const int lane = threadIdx.x & 63;
  const int b = w >> 10;
  const int h = (w >> 6) & 15;
  const int i = w & 63;
  const size_t base = (size_t)b * Sq * Dm + h * HDim;
  const u16* qp = q + base + lane;
  const u16* kp = k + base + lane;
  const u16* vp = v + base + i;
  const u16* gp = g + base + i;
  float state = 0.f;
  u16* op = ot + (size_t)w * Sq;

  for (int t0 = 0; t0 < Sq; t0 += 64) {
    float vv_pre = bf2f(vp[(size_t)(t0 + lane) * Dm]);  // 64 steps of v[i]
    float gg_pre = bf2f(gp[(size_t)(t0 + lane) * Dm]);  // 64 steps of g[i]
    float outreg = 0.f;
#pragma unroll 8
    for (int t = 0; t < 64; ++t) {
      float kf = bf2f(kp[(size_t)(t0 + t) * Dm]);
      float qf = bf2f(qp[(size_t)(t0 + t) * Dm]);
      float vv = __shfl(vv_pre, t, 64);
      float gg = __shfl(gg_pre, t, 64);
      state = fmaf(state, gg, vv * kf);
      float p = state * qf;
#pragma unroll
      for (int off = 32; off > 0; off >>= 1) p += __shfl_xor(p, off, 64);
      outreg = (lane == t) ? p : outreg;
    }
    op[t0 + lane] = f2bf(outreg);  // coalesced store
  }
}

// ------------------------------------------------------------------
// LayerNorm over D + SiLU output gate; reads ot transposed,
// writes bf16 yg[M][D] for the final GEMM.
__global__ __launch_bounds__(256) void ln_gate(
    const u16* __restrict__ ot, const u16* __restrict__ gp,
    const u16* __restrict__ gb, u16* __restrict__ yg) {
  const int m = blockIdx.x;                    // b*S + t
  const int b = m >> 11, t = m & (Sq - 1);
  const int tid = threadIdx.x, lane = tid & 63, wid = tid >> 6;
  const u16* gamma = gb + Dm;                  // canon vecs: [bias, gamma, beta]
  const u16* beta  = gb + 2 * Dm;
  float vals[4];
  float sum = 0.f, ss = 0.f;
#pragma unroll
  for (int j = 0; j < 4; ++j) {
    int d = tid + j * 256;
    vals[j] = bf2f(ot[(size_t)(b * Dm + d) * Sq + t]);
    sum += vals[j];
    ss += vals[j] * vals[j];
  }
#pragma unroll
  for (int off = 32; off > 0; off >>= 1) {
    sum += __shfl_xor(sum, off, 64);
    ss  += __shfl_xor(ss,  off, 64);
  }
  __shared__ float s1[4], s2[4];
  if (lane == 0) { s1[wid] = sum; s2[wid] = ss; }
  __syncthreads();
  float Sm = s1[0] + s1[1] + s1[2] + s1[3];
  float Ssq = s2[0] + s2[1] + s2[2] + s2[3];
  float mu = Sm * (1.f / Dm);
  float rstd = rsqrtf(Ssq * (1.f / Dm) - mu * mu + 1e-5f);
#pragma unroll
  for (int j = 0; j < 4; ++j) {
    int d = tid + j * 256;
    float y = (vals[j] - mu) * rstd * bf2f(gamma[d]) + bf2f(beta[d]);
    float zg = bf2f(gp[(size_t)m * Dm + d]);
    y *= zg / (1.f + __expf(-zg));             // silu gate
    yg[(size_t)m * Dm + d] = f2bf(y);
  }
}

// ------------------------------------------------------------------
extern "C" void kernel_launch(void* const* d_in, const int* in_sizes, int n_in,
                              void* d_out, int out_size, void* d_ws, size_t ws_size,
                              hipStream_t stream) {
  const u32* xw = (const u32*)d_in[0];   // x, dtype probed at runtime

  char* ws = (char*)d_ws;
  size_t off = 0;
  u16* wt = (u16*)(ws + off);   off += (size_t)6 * Dm * Dm * 2;   // 12.6 MB
  u16* xb = (u16*)(ws + off);   off += (size_t)M * Dm * 2;        // 16.8 MB each
  u16* q  = (u16*)(ws + off);   off += (size_t)M * Dm * 2;
  u16* k  = (u16*)(ws + off);   off += (size_t)M * Dm * 2;
  u16* v  = (u16*)(ws + off);   off += (size_t)M * Dm * 2;
  u16* g  = (u16*)(ws + off);   off += (size_t)M * Dm * 2;
  u16* gp = (u16*)(ws + off);   off += (size_t)M * Dm * 2;
  u16* vec = (u16*)(ws + off);  off += (size_t)3 * Dm * 2;        // bias,gamma,beta
  u16* ot = (u16*)d_out;  // scan output scratch in d_out (>=16.8MB both worlds)
  u16* yg = q;            // alias: q dead after scan; total ws ~ 113.3 MB

  convert_x<<<dim3(M * Dm / 2048), 256, 0, stream>>>(xw, xb);

  VPtrs vp3; vp3.v[0] = d_in[5]; vp3.v[1] = d_in[8]; vp3.v[2] = d_in[9];
  convert_vec<<<dim3(4, 3), 256, 0, stream>>>(vp3, vec, xw);

  WPtrs wp;
  wp.w[0] = d_in[1]; wp.w[1] = d_in[2]; wp.w[2] = d_in[3];
  wp.w[3] = d_in[4]; wp.w[4] = d_in[6]; wp.w[5] = d_in[7];
  transpose_w<<<dim3(Dm, 6), 256, 0, stream>>>(wp, wt, xw);

  GemmArgs ga;
  ga.e[0] = { wt + (size_t)0 * Dm * Dm, (void*)q,     0 };
  ga.e[1] = { wt + (size_t)1 * Dm * Dm, (void*)k,     0 };
  ga.e[2] = { wt + (size_t)2 * Dm * Dm, (void*)v,     0 };
  ga.e[3] = { wt + (size_t)3 * Dm * Dm, (void*)g,     1 };  // sigmoid(+bias)
  ga.e[4] = { wt + (size_t)4 * Dm * Dm, (void*)gp,    0 };  // gate proj
  ga.e[5] = { wt + (size_t)5 * Dm * Dm, d_out,        2 };  // final (dtype-adaptive)
  ga.bias = vec;

  gemm_bt<<<dim3(M / 128, NK / 128, 5), 256, 0, stream>>>(xb, ga, 0, xw);
  scan_kernel<<<dim3(1024), 256, 0, stream>>>(q, k, v, g, ot);
  ln_gate<<<dim3(M), 256, 0, stream>>>(ot, gp, vec, yg);
  gemm_bt<<<dim3(M / 128, NK / 128, 1), 256, 0, stream>>>(yg, ga, 5, xw);
}

// Round 5
// 485.308 us; speedup vs baseline: 2.2376x; 2.2376x over previous
//
#include <hip/hip_runtime.h>
#include <hip/hip_bf16.h>

typedef unsigned short u16;
typedef unsigned int u32;
using bf16x8 = __attribute__((ext_vector_type(8))) __bf16;
using u16x8  = __attribute__((ext_vector_type(8))) u16;
using f32x4  = __attribute__((ext_vector_type(4))) float;

#define DEV __device__ __forceinline__

constexpr int Bv = 4, Sq = 2048, Dm = 1024, Hh = 16, HDim = 64;
constexpr int M = Bv * Sq;      // 8192 rows
constexpr int NK = Dm;          // 1024 (N and K of every GEMM)

DEV float bf2f(u16 u) { union { u32 i; float f; } x; x.i = (u32)u << 16; return x.f; }
DEV u16 f2bf(float f) {
  union { float f; u32 i; } x; x.f = f;
  u32 r = (x.i + 0x7fff + ((x.i >> 16) & 1)) >> 16;  // RNE
  return (u16)r;
}

// Dtype probe: low u16 of each u32 of x. bf16-world: sane bf16 exp -> ~64/64
// hits. fp32-world: uniform mantissa bits -> ~10/64. Deterministic.
DEV bool detect_bf16(const u32* xw) {
  int c = 0;
#pragma unroll
  for (int i = 0; i < 64; ++i) {
    u32 e = (xw[i] >> 7) & 0xFF;
    c += (e >= 100 && e <= 140) ? 1 : 0;
  }
  return c >= 40;
}

// ------------------------------------------------------------------
__global__ __launch_bounds__(256) void convert_x(const u32* __restrict__ xw,
                                                 u16* __restrict__ xb) {
  const bool isb = detect_bf16(xw);
  const size_t i0 = ((size_t)blockIdx.x * 256 + threadIdx.x) * 8;
  if (isb) {
    *(u16x8*)(xb + i0) = *(const u16x8*)((const u16*)xw + i0);
  } else {
    const float* xf = (const float*)xw;
    u16x8 r;
#pragma unroll
    for (int j = 0; j < 8; ++j) r[j] = f2bf(xf[i0 + j]);
    *(u16x8*)(xb + i0) = r;
  }
}

struct VPtrs { const void* v[3]; };
__global__ __launch_bounds__(256) void convert_vec(VPtrs vp, u16* __restrict__ dst,
                                                   const u32* __restrict__ xw) {
  const bool isb = detect_bf16(xw);
  const int z = blockIdx.y, i = blockIdx.x * 256 + threadIdx.x;
  u16* d = dst + z * Dm;
  if (isb) d[i] = ((const u16*)vp.v[z])[i];
  else     d[i] = f2bf(((const float*)vp.v[z])[i]);
}

// ------------------------------------------------------------------
struct WPtrs { const void* w[6]; };
__global__ __launch_bounds__(256) void transpose_w(WPtrs wp, u16* __restrict__ wt,
                                                   const u32* __restrict__ xw) {
  const bool isb = detect_bf16(xw);
  const int z = blockIdx.y, kk = blockIdx.x, tid = threadIdx.x;
  u16* T = wt + (size_t)z * Dm * Dm;
  if (isb) {
    const u16* W = (const u16*)wp.w[z];
#pragma unroll
    for (int j = 0; j < 4; ++j) {
      int n = tid + j * 256;
      T[(size_t)n * Dm + kk] = W[(size_t)kk * Dm + n];
    }
  } else {
    const float* W = (const float*)wp.w[z];
#pragma unroll
    for (int j = 0; j < 4; ++j) {
      int n = tid + j * 256;
      T[(size_t)n * Dm + kk] = f2bf(W[(size_t)kk * Dm + n]);
    }
  }
}

// ------------------------------------------------------------------
// bf16 GEMM (unchanged from R4-passing version).
struct GemmEntry { const u16* wt; void* out; int mode; };
struct GemmArgs { GemmEntry e[6]; const u16* bias; };

__global__ __launch_bounds__(256) void gemm_bt(const u16* __restrict__ A, GemmArgs ga,
                                               int zbase, const u32* __restrict__ xw) {
  const int z = zbase + blockIdx.z;
  const u16* Bt = ga.e[z].wt;
  const int m0 = blockIdx.x * 128, n0 = blockIdx.y * 128;
  __shared__ __align__(16) u16 As[128 * 32];
  __shared__ __align__(16) u16 Bs[128 * 32];
  const int tid = threadIdx.x, lane = tid & 63;
  const int wm = ((tid >> 6) & 1) * 64, wn = ((tid >> 6) >> 1) * 64;
  const int lr = lane & 15, lk = (lane >> 4) * 8;

  f32x4 acc[4][4] = {};

  const int r0 = tid >> 2, c0 = (tid & 3) * 8;
  const u16* Ag = A + (size_t)(m0 + r0) * NK + c0;
  const u16* Bg = Bt + (size_t)(n0 + r0) * NK + c0;

  for (int kt = 0; kt < NK; kt += 32) {
    u16x8 a0 = *(const u16x8*)(Ag + kt);
    u16x8 a1 = *(const u16x8*)(Ag + (size_t)64 * NK + kt);
    u16x8 b0 = *(const u16x8*)(Bg + kt);
    u16x8 b1 = *(const u16x8*)(Bg + (size_t)64 * NK + kt);
    __syncthreads();
    *(u16x8*)(As + tid * 8) = a0;
    *(u16x8*)(As + 2048 + tid * 8) = a1;
    *(u16x8*)(Bs + tid * 8) = b0;
    *(u16x8*)(Bs + 2048 + tid * 8) = b1;
    __syncthreads();
    bf16x8 af[4], bfr[4];
#pragma unroll
    for (int i = 0; i < 4; ++i) af[i] = *(const bf16x8*)(As + (wm + i * 16 + lr) * 32 + lk);
#pragma unroll
    for (int j = 0; j < 4; ++j) bfr[j] = *(const bf16x8*)(Bs + (wn + j * 16 + lr) * 32 + lk);
#pragma unroll
    for (int i = 0; i < 4; ++i)
#pragma unroll
      for (int j = 0; j < 4; ++j)
        acc[i][j] = __builtin_amdgcn_mfma_f32_16x16x32_bf16(af[i], bfr[j], acc[i][j], 0, 0, 0);
  }

  const int mode = ga.e[z].mode;
  const int rb = m0 + wm + (lane >> 4) * 4;
  const int cb = n0 + wn + lr;
  if (mode == 0) {
    u16* O = (u16*)ga.e[z].out;
#pragma unroll
    for (int i = 0; i < 4; ++i)
#pragma unroll
      for (int j = 0; j < 4; ++j)
#pragma unroll
        for (int r = 0; r < 4; ++r)
          O[(size_t)(rb + i * 16 + r) * NK + cb + j * 16] = f2bf(acc[i][j][r]);
  } else if (mode == 1) {
    u16* O = (u16*)ga.e[z].out;
#pragma unroll
    for (int j = 0; j < 4; ++j) {
      float bb = bf2f(ga.bias[cb + j * 16]);
#pragma unroll
      for (int i = 0; i < 4; ++i)
#pragma unroll
        for (int r = 0; r < 4; ++r) {
          float val = acc[i][j][r] + bb;
          O[(size_t)(rb + i * 16 + r) * NK + cb + j * 16] = f2bf(1.f / (1.f + __expf(-val)));
        }
    }
  } else {
    const bool isb = detect_bf16(xw);
    if (isb) {
      u16* O = (u16*)ga.e[z].out;
#pragma unroll
      for (int i = 0; i < 4; ++i)
#pragma unroll
        for (int j = 0; j < 4; ++j)
#pragma unroll
          for (int r = 0; r < 4; ++r)
            O[(size_t)(rb + i * 16 + r) * NK + cb + j * 16] = f2bf(acc[i][j][r]);
    } else {
      float* O = (float*)ga.e[z].out;
#pragma unroll
      for (int i = 0; i < 4; ++i)
#pragma unroll
        for (int j = 0; j < 4; ++j)
#pragma unroll
          for (int r = 0; r < 4; ++r)
            O[(size_t)(rb + i * 16 + r) * NK + cb + j * 16] = acc[i][j][r];
    }
  }
}

// ------------------------------------------------------------------
// Chunked HGRN2 scan (FLA-style), MFMA-based. One 256-thr WG per (b,h).
// Chunk T=64. Per chunk: cumprod c[s][i]; vtil=v/c; S=QK^T masked ->P;
// OUT[i][tau] = c[tau][i]*(state0@Q^T + Vtil^T@P^T); state = cT*(state+Vtil^T@K).
// State in fp32 regs (C-layout), bf16 LDS round-trips (FLA-standard).
__global__ __launch_bounds__(256) void scan_chunked(
    const u16* __restrict__ q, const u16* __restrict__ k,
    const u16* __restrict__ v, const u16* __restrict__ g,
    u16* __restrict__ ot) {
  constexpr int SP = 72;  // tile stride (144B: 16B-aligned for b128)
  __shared__ __align__(16) u16 Qs[64 * SP];   // Q[tau][j]
  __shared__ __align__(16) u16 Ks[64 * SP];   // K[s][j]
  __shared__ __align__(16) u16 KT[64 * SP];   // K^T[j][s]
  __shared__ __align__(16) u16 VT[64 * SP];   // vtil^T[i][s]
  __shared__ __align__(16) u16 Ps[64 * SP];   // masked S [tau][s]
  __shared__ __align__(16) u16 SA[64 * SP];   // state bf16 [i][j]
  __shared__ __align__(16) float cF[64 * SP]; // cumprod c[s][i]
  __shared__ float segT[4][64];

  const int bh = blockIdx.x;            // 0..63
  const int b = bh >> 4, h = bh & 15;
  const size_t base = (size_t)b * Sq * Dm + h * HDim;
  const int tid = threadIdx.x, lane = tid & 63, w = tid >> 6;
  const int lr = lane & 15, quad = lane >> 4;

  const int Lrow = tid >> 2, Lcol = (tid & 3) * 16;  // Q/K/V tile loads
  const int Gi = tid & 63, Gseg = tid >> 6;          // gate cumprod rows

  float st[4][4];  // state[i=16w+quad*4+r][j=16nj+lr]
#pragma unroll
  for (int a = 0; a < 4; ++a)
#pragma unroll
    for (int r = 0; r < 4; ++r) st[a][r] = 0.f;

  for (int t0 = 0; t0 < Sq; t0 += 64) {
    // ---- stage 1: load Q,K (+K^T); gate local cumprod
    {
      const u16* qg = q + base + (size_t)(t0 + Lrow) * Dm + Lcol;
      const u16* kg = k + base + (size_t)(t0 + Lrow) * Dm + Lcol;
      u16x8 q0 = *(const u16x8*)qg, q1 = *(const u16x8*)(qg + 8);
      u16x8 k0 = *(const u16x8*)kg, k1 = *(const u16x8*)(kg + 8);
      *(u16x8*)(Qs + Lrow * SP + Lcol) = q0;
      *(u16x8*)(Qs + Lrow * SP + Lcol + 8) = q1;
      *(u16x8*)(Ks + Lrow * SP + Lcol) = k0;
      *(u16x8*)(Ks + Lrow * SP + Lcol + 8) = k1;
#pragma unroll
      for (int u = 0; u < 8; ++u) {
        KT[(Lcol + u) * SP + Lrow] = k0[u];
        KT[(Lcol + 8 + u) * SP + Lrow] = k1[u];
      }
      const u16* gg = g + base + (size_t)(t0 + Gseg * 16) * Dm + Gi;
      float p = 1.f;
#pragma unroll
      for (int u = 0; u < 16; ++u) {
        p *= bf2f(gg[(size_t)u * Dm]);
        cF[(Gseg * 16 + u) * SP + Gi] = p;
      }
      segT[Gseg][Gi] = p;
    }
    __syncthreads();
    // ---- stage 2: cumprod prefix fixup across segments
    if (Gseg > 0) {
      float pre = segT[0][Gi];
      for (int ss = 1; ss < Gseg; ++ss) pre *= segT[ss][Gi];
#pragma unroll
      for (int u = 0; u < 16; ++u) cF[(Gseg * 16 + u) * SP + Gi] *= pre;
    }
    __syncthreads();
    // ---- stage 3: vtil^T = v/c; dump state regs -> SA (bf16)
    {
      const u16* vg = v + base + (size_t)(t0 + Lrow) * Dm + Lcol;
      u16x8 v0 = *(const u16x8*)vg, v1 = *(const u16x8*)(vg + 8);
#pragma unroll
      for (int u = 0; u < 8; ++u) {
        float c0 = cF[Lrow * SP + Lcol + u];
        float c1 = cF[Lrow * SP + Lcol + 8 + u];
        VT[(Lcol + u) * SP + Lrow] = f2bf(bf2f(v0[u]) * __builtin_amdgcn_rcpf(c0));
        VT[(Lcol + 8 + u) * SP + Lrow] = f2bf(bf2f(v1[u]) * __builtin_amdgcn_rcpf(c1));
      }
#pragma unroll
      for (int nj = 0; nj < 4; ++nj)
#pragma unroll
        for (int r = 0; r < 4; ++r)
          SA[(16 * w + quad * 4 + r) * SP + 16 * nj + lr] = f2bf(st[nj][r]);
    }
    // ---- stage 4: S = Q K^T, causal mask -> Ps (no barrier needed between
    // 3 and 4: stage 4 reads only Qs/Ks, final since stage-1+barrier)
    {
      const u16* Ar = Qs + (16 * w + lr) * SP + quad * 8;
      bf16x8 a0 = *(const bf16x8*)Ar, a1 = *(const bf16x8*)(Ar + 32);
#pragma unroll
      for (int ns = 0; ns < 4; ++ns) {
        const u16* Br = Ks + (16 * ns + lr) * SP + quad * 8;
        f32x4 acc = {};
        acc = __builtin_amdgcn_mfma_f32_16x16x32_bf16(a0, *(const bf16x8*)Br, acc, 0, 0, 0);
        acc = __builtin_amdgcn_mfma_f32_16x16x32_bf16(a1, *(const bf16x8*)(Br + 32), acc, 0, 0, 0);
#pragma unroll
        for (int r = 0; r < 4; ++r) {
          int tau = 16 * w + quad * 4 + r, s = 16 * ns + lr;
          Ps[tau * SP + s] = f2bf((s <= tau) ? acc[r] : 0.f);
        }
      }
    }
    __syncthreads();
    // ---- stage 5: OUT[i][tau] & state update
    {
      const u16* SAr = SA + (16 * w + lr) * SP + quad * 8;
      const u16* VTr = VT + (16 * w + lr) * SP + quad * 8;
      bf16x8 aC0 = *(const bf16x8*)SAr, aC1 = *(const bf16x8*)(SAr + 32);
      bf16x8 aV0 = *(const bf16x8*)VTr, aV1 = *(const bf16x8*)(VTr + 32);
      u16* orow = ot + ((size_t)bh * 64) * Sq + t0;
#pragma unroll
      for (int nt = 0; nt < 4; ++nt) {
        const u16* Bq = Qs + (16 * nt + lr) * SP + quad * 8;
        const u16* Bp = Ps + (16 * nt + lr) * SP + quad * 8;
        f32x4 acc = {};
        acc = __builtin_amdgcn_mfma_f32_16x16x32_bf16(aC0, *(const bf16x8*)Bq, acc, 0, 0, 0);
        acc = __builtin_amdgcn_mfma_f32_16x16x32_bf16(aC1, *(const bf16x8*)(Bq + 32), acc, 0, 0, 0);
        acc = __builtin_amdgcn_mfma_f32_16x16x32_bf16(aV0, *(const bf16x8*)Bp, acc, 0, 0, 0);
        acc = __builtin_amdgcn_mfma_f32_16x16x32_bf16(aV1, *(const bf16x8*)(Bp + 32), acc, 0, 0, 0);
#pragma unroll
        for (int r = 0; r < 4; ++r) {
          int i = 16 * w + quad * 4 + r, tau = 16 * nt + lr;
          float o = acc[r] * cF[tau * SP + i];
          orow[(size_t)i * Sq + tau] = f2bf(o);
        }
      }
      float cT[4];
#pragma unroll
      for (int r = 0; r < 4; ++r) cT[r] = cF[63 * SP + 16 * w + quad * 4 + r];
#pragma unroll
      for (int nj = 0; nj < 4; ++nj) {
        const u16* Bk = KT + (16 * nj + lr) * SP + quad * 8;
        f32x4 acc = {};
        acc = __builtin_amdgcn_mfma_f32_16x16x32_bf16(aV0, *(const bf16x8*)Bk, acc, 0, 0, 0);
        acc = __builtin_amdgcn_mfma_f32_16x16x32_bf16(aV1, *(const bf16x8*)(Bk + 32), acc, 0, 0, 0);
#pragma unroll
        for (int r = 0; r < 4; ++r) st[nj][r] = cT[r] * (st[nj][r] + acc[r]);
      }
    }
    __syncthreads();
  }
}

// ------------------------------------------------------------------
__global__ __launch_bounds__(256) void ln_gate(
    const u16* __restrict__ ot, const u16* __restrict__ gp,
    const u16* __restrict__ gb, u16* __restrict__ yg) {
  const int m = blockIdx.x;
  const int b = m >> 11, t = m & (Sq - 1);
  const int tid = threadIdx.x, lane = tid & 63, wid = tid >> 6;
  const u16* gamma = gb + Dm;
  const u16* beta  = gb + 2 * Dm;
  float vals[4];
  float sum = 0.f, ss = 0.f;
#pragma unroll
  for (int j = 0; j < 4; ++j) {
    int d = tid + j * 256;
    vals[j] = bf2f(ot[(size_t)(b * Dm + d) * Sq + t]);
    sum += vals[j];
    ss += vals[j] * vals[j];
  }
#pragma unroll
  for (int off = 32; off > 0; off >>= 1) {
    sum += __shfl_xor(sum, off, 64);
    ss  += __shfl_xor(ss,  off, 64);
  }
  __shared__ float s1[4], s2[4];
  if (lane == 0) { s1[wid] = sum; s2[wid] = ss; }
  __syncthreads();
  float Sm = s1[0] + s1[1] + s1[2] + s1[3];
  float Ssq = s2[0] + s2[1] + s2[2] + s2[3];
  float mu = Sm * (1.f / Dm);
  float rstd = rsqrtf(Ssq * (1.f / Dm) - mu * mu + 1e-5f);
#pragma unroll
  for (int j = 0; j < 4; ++j) {
    int d = tid + j * 256;
    float y = (vals[j] - mu) * rstd * bf2f(gamma[d]) + bf2f(beta[d]);
    float zg = bf2f(gp[(size_t)m * Dm + d]);
    y *= zg / (1.f + __expf(-zg));
    yg[(size_t)m * Dm + d] = f2bf(y);
  }
}

// ------------------------------------------------------------------
extern "C" void kernel_launch(void* const* d_in, const int* in_sizes, int n_in,
                              void* d_out, int out_size, void* d_ws, size_t ws_size,
                              hipStream_t stream) {
  const u32* xw = (const u32*)d_in[0];

  char* ws = (char*)d_ws;
  size_t off = 0;
  u16* wt = (u16*)(ws + off);   off += (size_t)6 * Dm * Dm * 2;
  u16* xb = (u16*)(ws + off);   off += (size_t)M * Dm * 2;
  u16* q  = (u16*)(ws + off);   off += (size_t)M * Dm * 2;
  u16* k  = (u16*)(ws + off);   off += (size_t)M * Dm * 2;
  u16* v  = (u16*)(ws + off);   off += (size_t)M * Dm * 2;
  u16* g  = (u16*)(ws + off);   off += (size_t)M * Dm * 2;
  u16* gp = (u16*)(ws + off);   off += (size_t)M * Dm * 2;
  u16* vec = (u16*)(ws + off);  off += (size_t)3 * Dm * 2;
  u16* ot = (u16*)d_out;  // scan output scratch in d_out
  u16* yg = q;            // alias: q dead after scan

  convert_x<<<dim3(M * Dm / 2048), 256, 0, stream>>>(xw, xb);

  VPtrs vp3; vp3.v[0] = d_in[5]; vp3.v[1] = d_in[8]; vp3.v[2] = d_in[9];
  convert_vec<<<dim3(4, 3), 256, 0, stream>>>(vp3, vec, xw);

  WPtrs wp;
  wp.w[0] = d_in[1]; wp.w[1] = d_in[2]; wp.w[2] = d_in[3];
  wp.w[3] = d_in[4]; wp.w[4] = d_in[6]; wp.w[5] = d_in[7];
  transpose_w<<<dim3(Dm, 6), 256, 0, stream>>>(wp, wt, xw);

  GemmArgs ga;
  ga.e[0] = { wt + (size_t)0 * Dm * Dm, (void*)q,  0 };
  ga.e[1] = { wt + (size_t)1 * Dm * Dm, (void*)k,  0 };
  ga.e[2] = { wt + (size_t)2 * Dm * Dm, (void*)v,  0 };
  ga.e[3] = { wt + (size_t)3 * Dm * Dm, (void*)g,  1 };  // sigmoid(+bias)
  ga.e[4] = { wt + (size_t)4 * Dm * Dm, (void*)gp, 0 };  // gate proj
  ga.e[5] = { wt + (size_t)5 * Dm * Dm, d_out,     2 };  // final (dtype-adaptive)
  ga.bias = vec;

  gemm_bt<<<dim3(M / 128, NK / 128, 5), 256, 0, stream>>>(xb, ga, 0, xw);
  scan_chunked<<<dim3(64), 256, 0, stream>>>(q, k, v, g, ot);
  ln_gate<<<dim3(M), 256, 0, stream>>>(ot, gp, vec, yg);
  gemm_bt<<<dim3(M / 128, NK / 128, 1), 256, 0, stream>>>(yg, ga, 5, xw);
}